// Round 8
// baseline (342.824 us; speedup 1.0000x reference)
//
#include <hip/hip_runtime.h>
#include <hip/hip_bf16.h>

#define N_PTS 8192
#define KNN 8
#define GRID_DIM 32
#define NCELLS 32768
#define CELL_S 0.25f
#define GRID_LO (-4.0f)

typedef __attribute__((ext_vector_type(8))) short short8;
typedef __attribute__((ext_vector_type(4))) float float4v;
typedef unsigned long long u64;
typedef unsigned int u32;

static __device__ __forceinline__ short f2bf(float f) {
    unsigned u = __float_as_uint(f);
    unsigned r = (u + 0x7FFFu + ((u >> 16) & 1u)) >> 16;
    return (short)r;
}
static __device__ __forceinline__ float bf2f(short s) {
    return __uint_as_float(((unsigned)(unsigned short)s) << 16);
}

// monotone float -> u32 key (handles negative d' = |c|^2 - 2 q.c)
static __device__ __forceinline__ unsigned sortkey(float f) {
    unsigned u = __float_as_uint(f);
    return u ^ (((unsigned)((int)u >> 31)) | 0x80000000u);
}

static __device__ __forceinline__ void ins8(u64* best, u64 x) {
#pragma unroll
    for (int j = 0; j < 8; ++j) {
        const u64 lo = x < best[j] ? x : best[j];
        const u64 hi = x < best[j] ? best[j] : x;
        best[j] = lo; x = hi;
    }
}

// VGPR-pinned min update (r5 win; r7 law: only ONE query's 32-bucket state
// fits the ~44-VGPR budget -- never double it).
static __device__ __forceinline__ void vmin_acc(float& acc, float d) {
    asm("v_min_f32 %0, %0, %1" : "+v"(acc) : "v"(d));
}
static __device__ __forceinline__ void vsort2(float& a, float& x) {
    float lo, hi;
    asm("v_min_f32 %0, %2, %3\n\tv_max_f32 %1, %2, %3"
        : "=&v"(lo), "=v"(hi) : "v"(a), "v"(x));
    a = lo; x = hi;
}

static __device__ __forceinline__ int cell_coord(float v) {
    int c = (int)floorf((v - GRID_LO) * (1.0f / CELL_S));
    c = c < 0 ? 0 : c;
    c = c > GRID_DIM - 1 ? GRID_DIM - 1 : c;
    return c;
}
static __device__ __forceinline__ unsigned spread5(int v) {
    return (unsigned)((v & 1) | ((v & 2) << 2) | ((v & 4) << 4)
                    | ((v & 8) << 6) | ((v & 16) << 8));
}

// ---------------------------------------------------------------------------
// Dispatch 1: Morton cell histogram (sort is a pure permutation -- exactness
// never depends on it; it only concentrates partitions spatially so AABB
// pruning bites).
// ---------------------------------------------------------------------------
__global__ __launch_bounds__(256) void hist_kernel(const float* __restrict__ pos,
                                                   u32* __restrict__ cellCount,
                                                   unsigned short* __restrict__ cid)
{
    const int i = blockIdx.x * 256 + threadIdx.x;    // 0..16383
    const int b = i >> 13;
    const float px = pos[i * 3 + 0];
    const float py = pos[i * 3 + 1];
    const float pz = pos[i * 3 + 2];
    const unsigned m = spread5(cell_coord(px))
                     | (spread5(cell_coord(py)) << 1)
                     | (spread5(cell_coord(pz)) << 2);
    cid[i] = (unsigned short)m;
    atomicAdd(&cellCount[b * NCELLS + m], 1u);
}

// ---------------------------------------------------------------------------
// Dispatch 2: exclusive prefix sum (verified in r4).
// ---------------------------------------------------------------------------
__global__ __launch_bounds__(256) void scan_kernel(const u32* __restrict__ cellCount,
                                                   u32* __restrict__ cellStart)
{
    __shared__ u32 psum[256];
    const int b = blockIdx.x;
    const int tid = threadIdx.x;
    const u32* cnt = cellCount + b * NCELLS;
    u32* st = cellStart + b * (NCELLS + 1);

    u32 sum = 0;
    for (int j = 0; j < 128; ++j) sum += cnt[tid * 128 + j];
    psum[tid] = sum;
    __syncthreads();
    if (tid == 0) {
        u32 a = 0;
        for (int i = 0; i < 256; ++i) { const u32 t = psum[i]; psum[i] = a; a += t; }
    }
    __syncthreads();
    u32 run = psum[tid];
    for (int j = 0; j < 128; ++j) {
        st[tid * 128 + j] = run;
        run += cnt[tid * 128 + j];
    }
    if (tid == 255) st[NCELLS] = run;
}

// ---------------------------------------------------------------------------
// Dispatch 3: scatter into Morton order; w carries original index (verified
// in r4). Within-cell order arbitrary -- ties resolved by orig idx in keys.
// ---------------------------------------------------------------------------
__global__ __launch_bounds__(256) void scatter_kernel(const float* __restrict__ pos,
                                                      const unsigned short* __restrict__ cid,
                                                      const u32* __restrict__ cellStart,
                                                      u32* __restrict__ cellOff,
                                                      float4* __restrict__ sortedPos)
{
    const int i = blockIdx.x * 256 + threadIdx.x;
    const int b = i >> 13;
    const int li = i & 8191;
    const float px = pos[i * 3 + 0];
    const float py = pos[i * 3 + 1];
    const float pz = pos[i * 3 + 2];
    const int c = cid[i];
    const u32 dst = cellStart[b * (NCELLS + 1) + c] + atomicAdd(&cellOff[b * NCELLS + c], 1u);
    sortedPos[b * N_PTS + dst] = make_float4(px, py, pz, __int_as_float(li));
}

// ---------------------------------------------------------------------------
// Dispatch 4: blocks 0..127: AABB per 128-point sub-partition (64/batch).
// blocks 128..191: r-proxy per query = max d2 to 8 Morton-window neighbors
// (an achievable 8-candidate set => upper bound on the true 8-NN radius).
// ---------------------------------------------------------------------------
__global__ __launch_bounds__(256) void aabb_proxy(const float4* __restrict__ sortedPos,
                                                  float* __restrict__ aabb,
                                                  float* __restrict__ rprox)
{
    const int tid = threadIdx.x;
    if (blockIdx.x < 128) {
        __shared__ float red[6][128];
        const int b = blockIdx.x >> 6;               // batch
        const int sg = blockIdx.x & 63;              // sub-partition 0..63
        if (tid < 128) {
            const float4 c = sortedPos[b * N_PTS + sg * 128 + tid];
            red[0][tid] = c.x; red[1][tid] = c.y; red[2][tid] = c.z;
            red[3][tid] = c.x; red[4][tid] = c.y; red[5][tid] = c.z;
        }
        __syncthreads();
        for (int s = 64; s > 0; s >>= 1) {
            if (tid < s) {
                red[0][tid] = fminf(red[0][tid], red[0][tid + s]);
                red[1][tid] = fminf(red[1][tid], red[1][tid + s]);
                red[2][tid] = fminf(red[2][tid], red[2][tid + s]);
                red[3][tid] = fmaxf(red[3][tid], red[3][tid + s]);
                red[4][tid] = fmaxf(red[4][tid], red[4][tid + s]);
                red[5][tid] = fmaxf(red[5][tid], red[5][tid + s]);
            }
            __syncthreads();
        }
        if (tid == 0) {
            float* o = aabb + (b * 64 + sg) * 8;
            o[0] = red[0][0]; o[1] = red[1][0]; o[2] = red[2][0]; o[3] = 0.f;
            o[4] = red[3][0]; o[5] = red[4][0]; o[6] = red[5][0]; o[7] = 0.f;
        }
    } else {
        const int q = (blockIdx.x - 128) * 256 + tid;    // sorted global
        const int b = q >> 13, si = q & 8191;
        const float4* sp = sortedPos + b * N_PTS;
        const float4 me = sp[si];
        int lo = si - 4;
        lo = lo < 0 ? 0 : lo;
        lo = lo > N_PTS - 9 ? N_PTS - 9 : lo;
        float r = 0.f;
        for (int k = 0; k < 9; ++k) {
            const int j = lo + k;
            if (j == si) continue;
            const float4 c = sp[j];
            const float dx = c.x - me.x, dy = c.y - me.y, dz = c.z - me.z;
            r = fmaxf(r, fmaf(dx, dx, fmaf(dy, dy, dz * dz)));
        }
        rprox[q] = r;
    }
}

// ---------------------------------------------------------------------------
// Dispatch 5: knn_partial (1024 blocks) + conversions (4096 blocks), 1:4.
// knn: r5's EXACT dense-scan engine, gated per 128-cand sub-partition by a
// block-uniform AABB test: skip sub only if ALL 256 queries have
// dist2(q, AABB) > r_proxy(q)*(1+1e-5)+1e-6 -- skipped candidates are
// provably outside every query's top-8 (d2 >= lb > rhat >= r8, strict).
// Surviving subs staged compactly; inner loops (d', pinned buckets,
// threshold, collect, top-8, fallback) bit-identical to r5. Keys carry
// ORIGINAL indices (from sortedPos.w) -> tie order identical to r5.
// Skipped (p,qg) slices stay 0xFF (pre-memset) -> merge ignores them.
// ---------------------------------------------------------------------------
__global__ __launch_bounds__(256) void fused_knn_conv(const float4* __restrict__ sortedPos,
                                                      const float* __restrict__ aabb,
                                                      const float* __restrict__ rprox,
                                                      u64* __restrict__ partial,
                                                      const float* __restrict__ x,
                                                      const float* __restrict__ Wq,
                                                      const float* __restrict__ Wkv,
                                                      const float* __restrict__ Wout,
                                                      short* __restrict__ xb,
                                                      short* __restrict__ wqkvt,
                                                      short* __restrict__ woutt)
{
    __shared__ __align__(16) char smem[17984];
    const int tid = threadIdx.x;
    const int g5 = blockIdx.x / 5;
    const int r5 = blockIdx.x % 5;

    if (r5 == 0) {
        // ================= KNN block (1024 total) =========================
        float4* cand = (float4*)smem;                        // up to 512 f4
        unsigned short* sidx = (unsigned short*)(smem + 8192);   // 512 u16
        unsigned short* buf = (unsigned short*)(smem + 9216);    // [256][17]
        int* subkeep  = (int*)(smem + 17920);                // [4]
        int* keeplist = subkeep + 4;                         // [4]
        int* pnkeep   = subkeep + 8;

        const int kb = g5;                                   // 0..1023
        const int p   = kb & 15;
        const int qg  = kb >> 4;
        const int batch = qg >> 5;
        const int q_in_b = (qg & 31) * 256 + tid;            // SORTED index
        const float4* sp = sortedPos + batch * N_PTS;

        const float4 q4 = sp[q_in_b];
        const float rq = fmaf(rprox[batch * N_PTS + q_in_b], 1.00001f, 1e-6f);

        if (tid < 4) subkeep[tid] = 0;
        __syncthreads();
#pragma unroll
        for (int s = 0; s < 4; ++s) {
            const float* bb = aabb + ((batch * 16 + p) * 4 + s) * 8;
            const float ax = fmaxf(0.f, fmaxf(bb[0] - q4.x, q4.x - bb[4]));
            const float ay = fmaxf(0.f, fmaxf(bb[1] - q4.y, q4.y - bb[5]));
            const float az = fmaxf(0.f, fmaxf(bb[2] - q4.z, q4.z - bb[6]));
            const float lb = fmaf(ax, ax, fmaf(ay, ay, az * az));
            const unsigned long long bal = __ballot(lb <= rq);
            if ((tid & 63) == 0 && bal) subkeep[s] = 1;      // benign race
        }
        __syncthreads();
        if (tid == 0) {
            int n = 0;
            for (int s = 0; s < 4; ++s) if (subkeep[s]) keeplist[n++] = s;
            *pnkeep = n;
        }
        __syncthreads();
        const int nkeep = *pnkeep;
        if (nkeep == 0) return;                              // uniform skip

        // ---- compact staging of surviving subs ---------------------------
        for (int s = 0; s < nkeep; ++s) {
            const int sub = keeplist[s];
            if (tid < 128) {
                const float4 c = sp[p * 512 + sub * 128 + tid];
                cand[s * 128 + tid] = make_float4(c.x, c.y, c.z,
                    fmaf(c.x, c.x, fmaf(c.y, c.y, c.z * c.z)));
                sidx[s * 128 + tid] = (unsigned short)__float_as_int(c.w);
            }
        }
        __syncthreads();
        const int ncand = nkeep * 128;

        const float nqx = -2.0f * q4.x;
        const float nqy = -2.0f * q4.y;
        const float nqz = -2.0f * q4.z;

        // ---- pass 1: 32 rotating bucket minima (pinned) ------------------
        float bmin[32];
#pragma unroll
        for (int j = 0; j < 32; ++j) bmin[j] = 3.0e38f;

        for (int base = 0; base < ncand; base += 32) {
#pragma unroll
            for (int g = 0; g < 32; ++g) {
                const float4 c = cand[base + g];
                const float d = fmaf(c.x, nqx, fmaf(c.y, nqy, fmaf(c.z, nqz, c.w)));
                vmin_acc(bmin[g], d);
            }
        }

        // ---- threshold = 8th smallest bucket min -------------------------
        float t8[8];
#pragma unroll
        for (int j = 0; j < 8; ++j) t8[j] = 3.0e38f;
#pragma unroll
        for (int i = 0; i < 32; ++i) {
            float x_ = bmin[i];
#pragma unroll
            for (int j = 0; j < 8; ++j) vsort2(t8[j], x_);
        }
        const float t = t8[7];

        // ---- pass 2: exec-masked threshold collect -----------------------
        int cnt = 0;
        for (int base = 0; base < ncand; base += 32) {
#pragma unroll
            for (int g = 0; g < 32; ++g) {
                const float4 c = cand[base + g];
                const float d = fmaf(c.x, nqx, fmaf(c.y, nqy, fmaf(c.z, nqz, c.w)));
                if (d <= t) {
                    buf[tid * 17 + (cnt < 16 ? cnt : 16)] = (unsigned short)(base + g);
                    ++cnt;
                }
            }
        }

        // ---- exact top-8 over survivors ----------------------------------
        u64 best[8];
#pragma unroll
        for (int j = 0; j < 8; ++j) best[j] = ~0ULL;

        if (cnt <= 16) {
            for (int u = 0; u < cnt; ++u) {
                const int i = buf[tid * 17 + u];
                const float4 c = cand[i];
                const float d = fmaf(c.x, nqx, fmaf(c.y, nqy, fmaf(c.z, nqz, c.w)));
                ins8(best, ((u64)sortkey(d) << 32) | (u32)sidx[i]);
            }
        } else {
            for (int i = 0; i < ncand; ++i) {                // never taken
                const float4 c = cand[i];
                const float d = fmaf(c.x, nqx, fmaf(c.y, nqy, fmaf(c.z, nqz, c.w)));
                const u64 x_ = ((u64)sortkey(d) << 32) | (u32)sidx[i];
                if (x_ < best[7]) ins8(best, x_);
            }
        }

        const long qglob = (long)batch * N_PTS + q_in_b;     // sorted-global
#pragma unroll
        for (int j = 0; j < 8; ++j)
            partial[(long)(p * 8 + j) * 16384 + qglob] = best[j];   // coalesced

    } else {
        // ================= conv block (4096 total) ========================
        const int bid = g5 * 4 + (r5 - 1);
        if (bid < 2048) {
            const int i = bid * 256 + tid;
            const float4 a = ((const float4*)x)[i * 2];
            const float4 b = ((const float4*)x)[i * 2 + 1];
            short8 w = {f2bf(a.x), f2bf(a.y), f2bf(a.z), f2bf(a.w),
                        f2bf(b.x), f2bf(b.y), f2bf(b.z), f2bf(b.w)};
            ((short8*)xb)[i] = w;
        } else if (bid < 2560) {
            const int o = (bid - 2048) * 256 + tid;
            const int n = o >> 8, k = o & 255;
            wqkvt[o] = f2bf(Wq[(long)k * 512 + n]);
        } else if (bid < 3584) {
            const int o = (bid - 2560) * 256 + tid;
            const int n = o >> 8, k = o & 255;
            wqkvt[131072 + o] = f2bf(Wkv[(long)k * 1024 + n]);
        } else {
            const int o = (bid - 3584) * 256 + tid;
            const int n = o >> 9, k = o & 511;
            woutt[o] = f2bf(Wout[(long)k * 256 + n]);
        }
    }
}

// ---------------------------------------------------------------------------
// Dispatch 6: q/kv GEMM (1536 blocks) + knn_merge (first 64 blocks).
// merge scans 128 slices by SORTED query index, maps to original index via
// sortedPos.w for the idxo write (keys already hold original cand indices).
// ---------------------------------------------------------------------------
__global__ __launch_bounds__(256) void fused_gemm_merge(const short* __restrict__ A,
                                                        const short* __restrict__ Bt,
                                                        short* __restrict__ qall,
                                                        short* __restrict__ kvall,
                                                        const u64* __restrict__ partial,
                                                        const float4* __restrict__ sortedPos,
                                                        int* __restrict__ idxo)
{
    __shared__ short As[128][40];
    __shared__ short Bs[128][40];

    const int tid = threadIdx.x;

    if (blockIdx.x < 64) {
        const int q = blockIdx.x * 256 + tid;        // sorted global
        u64 best[8];
#pragma unroll
        for (int j = 0; j < 8; ++j) best[j] = ~0ULL;
        for (int s = 0; s < 128; ++s) {
            u64 x = partial[(long)s * 16384 + q];
            if (x < best[7]) ins8(best, x);
        }
        const int b = q >> 13;
        const int origq = __float_as_int(sortedPos[q].w);
#pragma unroll
        for (int j = 0; j < 8; ++j)
            idxo[((long)b * N_PTS + origq) * 8 + j] = (int)(best[j] & 0xFFFFFFFFu);
        return;
    }

    const int id = blockIdx.x - 64;
    const int bx = id % 12;
    const int by = id / 12;

    const int lane = tid & 63;
    const int wv   = tid >> 6;
    const int quad = lane >> 4;
    const int l15  = lane & 15;
    const int m0 = by * 128;
    const int n0 = bx * 128;
    const int mh = (wv & 1) * 64, nh = (wv >> 1) * 64;

    const int srow  = tid >> 1;
    const int shalf = (tid & 1) * 16;
    const int Kd = 256;

    float4v acc[4][4];
#pragma unroll
    for (int i = 0; i < 4; ++i)
#pragma unroll
        for (int j = 0; j < 4; ++j) acc[i][j] = (float4v)(0.f);

    for (int k0 = 0; k0 < Kd; k0 += 32) {
        const short8* asrc = (const short8*)(A + (long)(m0 + srow) * Kd + k0 + shalf);
        const short8* bsrc = (const short8*)(Bt + (long)(n0 + srow) * Kd + k0 + shalf);
        *(short8*)&As[srow][shalf]     = asrc[0];
        *(short8*)&As[srow][shalf + 8] = asrc[1];
        *(short8*)&Bs[srow][shalf]     = bsrc[0];
        *(short8*)&Bs[srow][shalf + 8] = bsrc[1];
        __syncthreads();

        short8 af[4], bfv[4];
#pragma unroll
        for (int i = 0; i < 4; ++i)
            af[i] = *(const short8*)&As[mh + i * 16 + l15][quad * 8];
#pragma unroll
        for (int j = 0; j < 4; ++j)
            bfv[j] = *(const short8*)&Bs[nh + j * 16 + l15][quad * 8];
#pragma unroll
        for (int i = 0; i < 4; ++i)
#pragma unroll
            for (int j = 0; j < 4; ++j)
                acc[i][j] = __builtin_amdgcn_mfma_f32_16x16x32_bf16(af[i], bfv[j], acc[i][j], 0, 0, 0);
        __syncthreads();
    }

    short* Cb;
    int stride, cb;
    if (n0 < 512) { Cb = qall;  stride = 512;  cb = n0; }
    else          { Cb = kvall; stride = 1024; cb = n0 - 512; }

#pragma unroll
    for (int i = 0; i < 4; ++i)
#pragma unroll
        for (int j = 0; j < 4; ++j) {
            const int col = cb + nh + j * 16 + l15;
#pragma unroll
            for (int r = 0; r < 4; ++r) {
                const int row = m0 + mh + i * 16 + quad * 4 + r;
                Cb[(long)row * stride + col] = f2bf(acc[i][j][r]);
            }
        }
}

// ---------------------------------------------------------------------------
// Fused KNN attention (unchanged).
// ---------------------------------------------------------------------------
__global__ __launch_bounds__(256) void attn_kernel(const short* qall,
                                                   const short* __restrict__ kvall,
                                                   const int* __restrict__ idxp,
                                                   short* outp)
{
    __shared__ float attn_s[4][8][8];
    const int wave = threadIdx.x >> 6;
    const int lane = threadIdx.x & 63;
    const int g = blockIdx.x * 4 + wave;
    const int b = g >> 13;
    const int* myidx = idxp + (long)g * 8;

    {
        const int h = lane >> 3;
        const int k = lane & 7;
        const int j = myidx[k];
        const short8* qrow = (const short8*)(qall + (long)g * 512 + h * 64);
        const short8* krow = (const short8*)(kvall + ((long)(b * N_PTS + j)) * 1024 + h * 64);

        float dot = 0.f;
#pragma unroll
        for (int c = 0; c < 8; ++c) {
            const short8 qv = qrow[c];
            const short8 kv = krow[c];
#pragma unroll
            for (int e = 0; e < 8; ++e)
                dot = fmaf(bf2f(qv[e]), bf2f(kv[e]), dot);
        }
        dot *= 0.125f;

        float m = dot;
#pragma unroll
        for (int off = 1; off < 8; off <<= 1)
            m = fmaxf(m, __shfl_xor(m, off, 8));
        const float e = __expf(dot - m);
        float ssum = e;
#pragma unroll
        for (int off = 1; off < 8; off <<= 1)
            ssum += __shfl_xor(ssum, off, 8);
        attn_s[wave][h][k] = e / ssum;
    }
    __syncthreads();

    const int d8 = lane * 8;
    const int h2 = lane >> 3;
    float o[8] = {0.f, 0.f, 0.f, 0.f, 0.f, 0.f, 0.f, 0.f};
#pragma unroll
    for (int kk = 0; kk < 8; ++kk) {
        const int jj = myidx[kk];
        const float w = attn_s[wave][h2][kk];
        const short8 v = *(const short8*)(kvall + ((long)(b * N_PTS + jj)) * 1024 + 512 + d8);
#pragma unroll
        for (int e = 0; e < 8; ++e)
            o[e] = fmaf(w, bf2f(v[e]), o[e]);
    }
    short8 ov = {f2bf(o[0]), f2bf(o[1]), f2bf(o[2]), f2bf(o[3]),
                 f2bf(o[4]), f2bf(o[5]), f2bf(o[6]), f2bf(o[7])};
    *(short8*)(outp + (long)g * 512 + d8) = ov;
}

// ---------------------------------------------------------------------------
// Out-projection GEMM (unchanged).
// ---------------------------------------------------------------------------
__global__ __launch_bounds__(256) void gemm_out(const short* __restrict__ A,
                                                const short* __restrict__ Bt,
                                                const float* __restrict__ bias,
                                                float* __restrict__ C,
                                                int N, int Kd)
{
    __shared__ short As[128][40];
    __shared__ short Bs[128][40];

    const int tid  = threadIdx.x;
    const int lane = tid & 63;
    const int wv   = tid >> 6;
    const int quad = lane >> 4;
    const int l15  = lane & 15;
    const int m0 = blockIdx.y * 128;
    const int n0 = blockIdx.x * 128;
    const int mh = (wv & 1) * 64, nh = (wv >> 1) * 64;

    const int srow  = tid >> 1;
    const int shalf = (tid & 1) * 16;

    float4v acc[4][4];
#pragma unroll
    for (int i = 0; i < 4; ++i)
#pragma unroll
        for (int j = 0; j < 4; ++j) acc[i][j] = (float4v)(0.f);

    for (int k0 = 0; k0 < Kd; k0 += 32) {
        const short8* asrc = (const short8*)(A + (long)(m0 + srow) * Kd + k0 + shalf);
        const short8* bsrc = (const short8*)(Bt + (long)(n0 + srow) * Kd + k0 + shalf);
        *(short8*)&As[srow][shalf]     = asrc[0];
        *(short8*)&As[srow][shalf + 8] = asrc[1];
        *(short8*)&Bs[srow][shalf]     = bsrc[0];
        *(short8*)&Bs[srow][shalf + 8] = bsrc[1];
        __syncthreads();

        short8 af[4], bfv[4];
#pragma unroll
        for (int i = 0; i < 4; ++i)
            af[i] = *(const short8*)&As[mh + i * 16 + l15][quad * 8];
#pragma unroll
        for (int j = 0; j < 4; ++j)
            bfv[j] = *(const short8*)&Bs[nh + j * 16 + l15][quad * 8];
#pragma unroll
        for (int i = 0; i < 4; ++i)
#pragma unroll
            for (int j = 0; j < 4; ++j)
                acc[i][j] = __builtin_amdgcn_mfma_f32_16x16x32_bf16(af[i], bfv[j], acc[i][j], 0, 0, 0);
        __syncthreads();
    }

#pragma unroll
    for (int i = 0; i < 4; ++i)
#pragma unroll
        for (int j = 0; j < 4; ++j) {
            const int col = n0 + nh + j * 16 + l15;
            const float bb = bias[col];
#pragma unroll
            for (int r = 0; r < 4; ++r) {
                const int row = m0 + mh + i * 16 + quad * 4 + r;
                C[(long)row * N + col] = acc[i][j][r] + bb;
            }
        }
}

// ---------------------------------------------------------------------------
extern "C" void kernel_launch(void* const* d_in, const int* in_sizes, int n_in,
                              void* d_out, int out_size, void* d_ws, size_t ws_size,
                              hipStream_t stream)
{
    const float* x    = (const float*)d_in[0];  // [2,8192,256]
    const float* pos  = (const float*)d_in[1];  // [2,8192,3]
    const float* Wq   = (const float*)d_in[2];  // [256,512]
    const float* Wkv  = (const float*)d_in[3];  // [256,1024]
    const float* Wout = (const float*)d_in[4];  // [512,256]
    const float* bout = (const float*)d_in[5];  // [256]
    float* out = (float*)d_out;                 // [2,8192,256] f32

    const int M = 16384;

    // workspace layout:
    char* ws = (char*)d_ws;
    int*   idxp  = (int*)ws;                          ws += 1 << 19;             // 512 KB
    short* qall  = (short*)ws;                        ws += (long)M * 512 * 2;   // 16 MB
    short* kvall = (short*)ws;                        ws += (long)M * 1024 * 2;  // 32 MB
    short* xb    = (short*)ws;                        ws += (long)M * 256 * 2;   // 8 MB
    short* wqkvt = (short*)ws;                        ws += 1536 * 256 * 2;      // 768 KB
    short* woutt = (short*)ws;                        ws += 256 * 512 * 2;       // 256 KB
    u64*  partial = (u64*)ws;                         ws += (long)128 * 16384 * 8; // 16 MB
    u32*  cellCount = (u32*)ws;                       ws += 2L * NCELLS * 4;     // 256 KB
    u32*  cellOff   = (u32*)ws;                       ws += 2L * NCELLS * 4;     // 256 KB
    u32*  cellStart = (u32*)ws;                       ws += 2L * (NCELLS + 1) * 4 + 56;
    unsigned short* cid = (unsigned short*)ws;        ws += (long)M * 2;         // 32 KB
    float4* sortedPos = (float4*)ws;                  ws += (long)M * 16;        // 256 KB
    float* aabb  = (float*)ws;                        ws += 2L * 64 * 8 * 4;     // 4 KB
    float* rprox = (float*)ws;                        ws += (long)M * 4;         // 64 KB

    hipMemsetAsync(cellCount, 0, 4L * NCELLS * 4, stream);       // count+off
    hipMemsetAsync(partial, 0xFF, 128L * 16384 * 8, stream);     // skip default

    hist_kernel<<<64, 256, 0, stream>>>(pos, cellCount, cid);
    scan_kernel<<<2, 256, 0, stream>>>(cellCount, cellStart);
    scatter_kernel<<<64, 256, 0, stream>>>(pos, cid, cellStart, cellOff, sortedPos);
    aabb_proxy<<<192, 256, 0, stream>>>(sortedPos, aabb, rprox);
    fused_knn_conv<<<5120, 256, 0, stream>>>(sortedPos, aabb, rprox, partial,
                                             x, Wq, Wkv, Wout, xb, wqkvt, woutt);
    fused_gemm_merge<<<1600, 256, 0, stream>>>(xb, wqkvt, qall, kvall, partial,
                                               sortedPos, idxp);
    attn_kernel<<<M / 4, 256, 0, stream>>>(qall, kvall, idxp, qall);   // in-place
    gemm_out<<<dim3(2, 128), 256, 0, stream>>>(qall, woutt, bout, out, 256, 512);
}

// Round 9
// 318.747 us; speedup vs baseline: 1.0755x; 1.0755x over previous
//
#include <hip/hip_runtime.h>
#include <hip/hip_bf16.h>

#define N_PTS 8192
#define KNN 8

typedef __attribute__((ext_vector_type(8))) short short8;
typedef __attribute__((ext_vector_type(4))) float float4v;
typedef unsigned long long u64;
typedef unsigned int u32;

// f32 -> bf16 round-to-nearest-even (finite inputs only)
static __device__ __forceinline__ short f2bf(float f) {
    unsigned u = __float_as_uint(f);
    unsigned r = (u + 0x7FFFu + ((u >> 16) & 1u)) >> 16;
    return (short)r;
}
static __device__ __forceinline__ float bf2f(short s) {
    return __uint_as_float(((unsigned)(unsigned short)s) << 16);
}

// monotone float -> u32 key (handles negative d' = |c|^2 - 2 q.c)
static __device__ __forceinline__ unsigned sortkey(float f) {
    unsigned u = __float_as_uint(f);
    return u ^ (((unsigned)((int)u >> 31)) | 0x80000000u);
}

static __device__ __forceinline__ void ins8(u64* best, u64 x) {
#pragma unroll
    for (int j = 0; j < 8; ++j) {
        const u64 lo = x < best[j] ? x : best[j];
        const u64 hi = x < best[j] ? best[j] : x;
        best[j] = lo; x = hi;
    }
}

// VGPR-pinned min update (r5 win: stops AGPR demotion of persistent state;
// r7 law: only ONE query's 32-bucket state fits the ~44-VGPR budget).
static __device__ __forceinline__ void vmin_acc(float& acc, float d) {
    asm("v_min_f32 %0, %0, %1" : "+v"(acc) : "v"(d));
}
// VGPR-pinned compare-exchange for the insertion networks.
static __device__ __forceinline__ void vsort2(float& a, float& x) {
    float lo, hi;
    asm("v_min_f32 %0, %2, %3\n\tv_max_f32 %1, %2, %3"
        : "=&v"(lo), "=v"(hi) : "v"(a), "v"(x));
    a = lo; x = hi;
}

// ---------------------------------------------------------------------------
// Dispatch 0: pack positions as (x, y, z, |c|^2) float4 (r2-verified).
// |c|^2 formula bit-identical to r5's LDS packer -> d' selection invariant.
// ---------------------------------------------------------------------------
__global__ __launch_bounds__(256) void pack_pos(const float* __restrict__ pos,
                                                float4* __restrict__ packed)
{
    const int i = blockIdx.x * 256 + threadIdx.x;   // 0..16383
    const float x = pos[i * 3 + 0];
    const float y = pos[i * 3 + 1];
    const float z = pos[i * 3 + 2];
    packed[i] = make_float4(x, y, z, fmaf(x, x, fmaf(y, y, z * z)));
}

// ---------------------------------------------------------------------------
// Dispatch 1: knn_partial (1024 blocks) + all f32->bf16 conversions (4096
// blocks), 1:4 interleave (r5 structure).
//
// knn (round 9): r5 engine with CHUNKED buckets (bucket = idx>>4, 16 cands
// per chunk). Pass 1: 512 broadcast LDS reads, 32 pinned chunk minima.
// Threshold t = 8th smallest chunk min (same >=8-survivor / top8-subset
// proof as r5). KEY FACT: a survivor (d<=t) can only live in a chunk with
// bmin<=t, and exactly 8 chunks qualify barring float ties -> pass 2 scans
// only 8*16=128 candidates per lane, gathered from GLOBAL packed[] (L1-hot
// 8KB partition slice; per-lane LDS gather would be a 32-way bank conflict).
// Qualifying chunk ids bit-packed 5b x 8 into a u64 (static extraction).
// m!=8 (ties) or cnt>16 -> exact full LDS rescan fallback (never taken).
// Keys/tie-order bit-identical to r5.
// ---------------------------------------------------------------------------
__global__ __launch_bounds__(256) void fused_knn_conv(const float4* __restrict__ packed,
                                                      u64* __restrict__ partial,
                                                      const float* __restrict__ x,
                                                      const float* __restrict__ Wq,
                                                      const float* __restrict__ Wkv,
                                                      const float* __restrict__ Wout,
                                                      short* __restrict__ xb,
                                                      short* __restrict__ wqkvt,
                                                      short* __restrict__ woutt)
{
    __shared__ __align__(16) char smem[16896];
    const int tid = threadIdx.x;
    const int g5 = blockIdx.x / 5;
    const int r5 = blockIdx.x % 5;

    if (r5 == 0) {
        // ================= KNN block (1024 total) =========================
        const int kb = g5;                       // 0..1023
        float4* cand = (float4*)smem;            // 512 x (x,y,z,|c|^2) = 8192 B
        unsigned short* buf = (unsigned short*)(smem + 8192);  // [256][17] u16

        const int p   = kb & 15;
        const int qg  = kb >> 4;
        const int batch = qg >> 5;
        const int q_in_b = (qg & 31) * 256 + tid;
        const float4* __restrict__ cp = packed + batch * N_PTS + p * 512;

        // stage partition into LDS (coalesced, 2 float4 per thread)
        cand[tid]       = cp[tid];
        cand[tid + 256] = cp[tid + 256];
        __syncthreads();

        const float4 q4 = packed[batch * N_PTS + q_in_b];
        const float nqx = -2.0f * q4.x;
        const float nqy = -2.0f * q4.y;
        const float nqz = -2.0f * q4.z;

        // ---- pass 1: 32 CHUNK minima (chunk g = cands [16g,16g+16)) ------
        float bmin[32];
#pragma unroll
        for (int j = 0; j < 32; ++j) bmin[j] = 3.0e38f;

        for (int k = 0; k < 16; ++k) {
#pragma unroll
            for (int g = 0; g < 32; ++g) {
                const float4 c = cand[g * 16 + k];        // broadcast read
                const float d = fmaf(c.x, nqx, fmaf(c.y, nqy, fmaf(c.z, nqz, c.w)));
                vmin_acc(bmin[g], d);
            }
        }

        // ---- threshold = 8th smallest chunk min --------------------------
        float t8[8];
#pragma unroll
        for (int j = 0; j < 8; ++j) t8[j] = 3.0e38f;
#pragma unroll
        for (int i = 0; i < 32; ++i) {
            float x_ = bmin[i];
#pragma unroll
            for (int j = 0; j < 8; ++j)
                vsort2(t8[j], x_);
        }
        const float t = t8[7];

        // ---- pack qualifying chunk ids (bmin <= t), 5 bits each ----------
        u64 sel = 0;
        int m = 0;
#pragma unroll
        for (int i = 0; i < 32; ++i) {
            if (bmin[i] <= t) { sel |= ((u64)i) << (5 * m); ++m; }
        }

        int cnt = 0;
        bool fullscan = (m > 8);                 // float-tie pathology only
        if (!fullscan) {
            // ---- pass 2: scan 8 qualifying chunks from GLOBAL (L1-hot) ---
#pragma unroll
            for (int u = 0; u < 8; ++u) {
                if (u < m) {                     // m == 8 generically (uniform)
                    const int c0 = ((int)(sel >> (5 * u)) & 31) * 16;
#pragma unroll
                    for (int k = 0; k < 16; ++k) {
                        const float4 c = cp[c0 + k];       // per-lane gather
                        const float d = fmaf(c.x, nqx, fmaf(c.y, nqy, fmaf(c.z, nqz, c.w)));
                        if (d <= t) {
                            buf[tid * 17 + (cnt < 16 ? cnt : 16)] = (unsigned short)(c0 + k);
                            ++cnt;
                        }
                    }
                }
            }
            fullscan = (cnt > 16);
        }

        // ---- exact top-8 over survivors ----------------------------------
        u64 best[8];
#pragma unroll
        for (int j = 0; j < 8; ++j) best[j] = ~0ULL;

        if (!fullscan) {
            for (int u = 0; u < cnt; ++u) {
                const int i = buf[tid * 17 + u];
                const float4 c = cp[i];                    // L1/L2-hot
                const float d = fmaf(c.x, nqx, fmaf(c.y, nqy, fmaf(c.z, nqz, c.w)));
                ins8(best, ((u64)sortkey(d) << 32) | (unsigned)(p * 512 + i));
            }
        } else {
            for (int i = 0; i < 512; ++i) {      // statistically-never fallback
                const float4 c = cand[i];
                const float d = fmaf(c.x, nqx, fmaf(c.y, nqy, fmaf(c.z, nqz, c.w)));
                const u64 x_ = ((u64)sortkey(d) << 32) | (unsigned)(p * 512 + i);
                if (x_ < best[7]) ins8(best, x_);
            }
        }

        const long qglob = (long)batch * N_PTS + q_in_b;
#pragma unroll
        for (int j = 0; j < 8; ++j)
            partial[(long)(p * 8 + j) * 16384 + qglob] = best[j];   // coalesced

    } else {
        // ================= conv block (4096 total, LDS-unused) ============
        const int bid = g5 * 4 + (r5 - 1);      // 0..4095
        if (bid < 2048) {
            const int i = bid * 256 + tid;
            const float4 a = ((const float4*)x)[i * 2];
            const float4 b = ((const float4*)x)[i * 2 + 1];
            short8 w = {f2bf(a.x), f2bf(a.y), f2bf(a.z), f2bf(a.w),
                        f2bf(b.x), f2bf(b.y), f2bf(b.z), f2bf(b.w)};
            ((short8*)xb)[i] = w;
        } else if (bid < 2560) {
            const int o = (bid - 2048) * 256 + tid;      // n*256+k, n<512
            const int n = o >> 8, k = o & 255;
            wqkvt[o] = f2bf(Wq[(long)k * 512 + n]);
        } else if (bid < 3584) {
            const int o = (bid - 2560) * 256 + tid;      // n*256+k, n<1024
            const int n = o >> 8, k = o & 255;
            wqkvt[131072 + o] = f2bf(Wkv[(long)k * 1024 + n]);
        } else {
            const int o = (bid - 3584) * 256 + tid;      // n*512+k, n<256
            const int n = o >> 9, k = o & 511;
            woutt[o] = f2bf(Wout[(long)k * 256 + n]);
        }
    }
}

// ---------------------------------------------------------------------------
// Dispatch 2: q/kv GEMM (1536 blocks) + knn_merge (first 64 blocks).
// merge uses zero LDS; co-resident with the gemm flood it hides completely.
// gemm: xb[16384,256] x wqkvt[1536,256]^T, 128x128 tile, BK=32, 4 waves 2x2,
// 16x16x32 MFMA; cols [0,512) -> qall (stride 512), [512,1536) -> kvall.
// ---------------------------------------------------------------------------
__global__ __launch_bounds__(256) void fused_gemm_merge(const short* __restrict__ A,
                                                        const short* __restrict__ Bt,
                                                        short* __restrict__ qall,
                                                        short* __restrict__ kvall,
                                                        const u64* __restrict__ partial,
                                                        int* __restrict__ idxo)
{
    __shared__ short As[128][40];
    __shared__ short Bs[128][40];

    const int tid = threadIdx.x;

    if (blockIdx.x < 64) {
        // ================= merge block (zero LDS) =========================
        const int q = blockIdx.x * 256 + tid;
        u64 best[8];
#pragma unroll
        for (int j = 0; j < 8; ++j) best[j] = ~0ULL;
        for (int s = 0; s < 128; ++s) {
            u64 x = partial[(long)s * 16384 + q];
            if (x < best[7]) ins8(best, x);
        }
#pragma unroll
        for (int j = 0; j < 8; ++j)
            idxo[(long)q * 8 + j] = (int)(best[j] & 0xFFFFFFFFu);
        return;
    }

    // ================= GEMM block (1536 total) ============================
    const int id = blockIdx.x - 64;
    const int bx = id % 12;
    const int by = id / 12;

    const int lane = tid & 63;
    const int wv   = tid >> 6;
    const int quad = lane >> 4;
    const int l15  = lane & 15;
    const int m0 = by * 128;
    const int n0 = bx * 128;
    const int mh = (wv & 1) * 64, nh = (wv >> 1) * 64;

    const int srow  = tid >> 1;
    const int shalf = (tid & 1) * 16;
    const int Kd = 256;

    float4v acc[4][4];
#pragma unroll
    for (int i = 0; i < 4; ++i)
#pragma unroll
        for (int j = 0; j < 4; ++j) acc[i][j] = (float4v)(0.f);

    for (int k0 = 0; k0 < Kd; k0 += 32) {
        const short8* asrc = (const short8*)(A + (long)(m0 + srow) * Kd + k0 + shalf);
        const short8* bsrc = (const short8*)(Bt + (long)(n0 + srow) * Kd + k0 + shalf);
        *(short8*)&As[srow][shalf]     = asrc[0];
        *(short8*)&As[srow][shalf + 8] = asrc[1];
        *(short8*)&Bs[srow][shalf]     = bsrc[0];
        *(short8*)&Bs[srow][shalf + 8] = bsrc[1];
        __syncthreads();

        short8 af[4], bfv[4];
#pragma unroll
        for (int i = 0; i < 4; ++i)
            af[i] = *(const short8*)&As[mh + i * 16 + l15][quad * 8];
#pragma unroll
        for (int j = 0; j < 4; ++j)
            bfv[j] = *(const short8*)&Bs[nh + j * 16 + l15][quad * 8];
#pragma unroll
        for (int i = 0; i < 4; ++i)
#pragma unroll
            for (int j = 0; j < 4; ++j)
                acc[i][j] = __builtin_amdgcn_mfma_f32_16x16x32_bf16(af[i], bfv[j], acc[i][j], 0, 0, 0);
        __syncthreads();
    }

    short* Cb;
    int stride, cb;
    if (n0 < 512) { Cb = qall;  stride = 512;  cb = n0; }
    else          { Cb = kvall; stride = 1024; cb = n0 - 512; }

#pragma unroll
    for (int i = 0; i < 4; ++i)
#pragma unroll
        for (int j = 0; j < 4; ++j) {
            const int col = cb + nh + j * 16 + l15;
#pragma unroll
            for (int r = 0; r < 4; ++r) {
                const int row = m0 + mh + i * 16 + quad * 4 + r;
                Cb[(long)row * stride + col] = f2bf(acc[i][j][r]);
            }
        }
}

// ---------------------------------------------------------------------------
// Fused KNN attention, bf16 storage / f32 math (unchanged since round 5).
// ---------------------------------------------------------------------------
__global__ __launch_bounds__(256) void attn_kernel(const short* qall,
                                                   const short* __restrict__ kvall,
                                                   const int* __restrict__ idxp,
                                                   short* outp)
{
    __shared__ float attn_s[4][8][8];
    const int wave = threadIdx.x >> 6;
    const int lane = threadIdx.x & 63;
    const int g = blockIdx.x * 4 + wave;
    const int b = g >> 13;
    const int* myidx = idxp + (long)g * 8;

    {
        const int h = lane >> 3;
        const int k = lane & 7;
        const int j = myidx[k];
        const short8* qrow = (const short8*)(qall + (long)g * 512 + h * 64);
        const short8* krow = (const short8*)(kvall + ((long)(b * N_PTS + j)) * 1024 + h * 64);

        float dot = 0.f;
#pragma unroll
        for (int c = 0; c < 8; ++c) {
            const short8 qv = qrow[c];
            const short8 kv = krow[c];
#pragma unroll
            for (int e = 0; e < 8; ++e)
                dot = fmaf(bf2f(qv[e]), bf2f(kv[e]), dot);
        }
        dot *= 0.125f;

        float m = dot;
#pragma unroll
        for (int off = 1; off < 8; off <<= 1)
            m = fmaxf(m, __shfl_xor(m, off, 8));
        const float e = __expf(dot - m);
        float ssum = e;
#pragma unroll
        for (int off = 1; off < 8; off <<= 1)
            ssum += __shfl_xor(ssum, off, 8);
        attn_s[wave][h][k] = e / ssum;
    }
    __syncthreads();                      // drains q reads before aliased writes

    const int d8 = lane * 8;
    const int h2 = lane >> 3;
    float o[8] = {0.f, 0.f, 0.f, 0.f, 0.f, 0.f, 0.f, 0.f};
#pragma unroll
    for (int kk = 0; kk < 8; ++kk) {
        const int jj = myidx[kk];
        const float w = attn_s[wave][h2][kk];
        const short8 v = *(const short8*)(kvall + ((long)(b * N_PTS + jj)) * 1024 + 512 + d8);
#pragma unroll
        for (int e = 0; e < 8; ++e)
            o[e] = fmaf(w, bf2f(v[e]), o[e]);
    }
    short8 ov = {f2bf(o[0]), f2bf(o[1]), f2bf(o[2]), f2bf(o[3]),
                 f2bf(o[4]), f2bf(o[5]), f2bf(o[6]), f2bf(o[7])};
    *(short8*)(outp + (long)g * 512 + d8) = ov;
}

// ---------------------------------------------------------------------------
// Out-projection bf16 MFMA GEMM: C f32 = A[M,512] x Bt[256,512]^T + bias.
// ---------------------------------------------------------------------------
__global__ __launch_bounds__(256) void gemm_out(const short* __restrict__ A,
                                                const short* __restrict__ Bt,
                                                const float* __restrict__ bias,
                                                float* __restrict__ C,
                                                int N, int Kd)
{
    __shared__ short As[128][40];
    __shared__ short Bs[128][40];

    const int tid  = threadIdx.x;
    const int lane = tid & 63;
    const int wv   = tid >> 6;
    const int quad = lane >> 4;
    const int l15  = lane & 15;
    const int m0 = blockIdx.y * 128;
    const int n0 = blockIdx.x * 128;
    const int mh = (wv & 1) * 64, nh = (wv >> 1) * 64;

    const int srow  = tid >> 1;
    const int shalf = (tid & 1) * 16;

    float4v acc[4][4];
#pragma unroll
    for (int i = 0; i < 4; ++i)
#pragma unroll
        for (int j = 0; j < 4; ++j) acc[i][j] = (float4v)(0.f);

    for (int k0 = 0; k0 < Kd; k0 += 32) {
        const short8* asrc = (const short8*)(A + (long)(m0 + srow) * Kd + k0 + shalf);
        const short8* bsrc = (const short8*)(Bt + (long)(n0 + srow) * Kd + k0 + shalf);
        *(short8*)&As[srow][shalf]     = asrc[0];
        *(short8*)&As[srow][shalf + 8] = asrc[1];
        *(short8*)&Bs[srow][shalf]     = bsrc[0];
        *(short8*)&Bs[srow][shalf + 8] = bsrc[1];
        __syncthreads();

        short8 af[4], bfv[4];
#pragma unroll
        for (int i = 0; i < 4; ++i)
            af[i] = *(const short8*)&As[mh + i * 16 + l15][quad * 8];
#pragma unroll
        for (int j = 0; j < 4; ++j)
            bfv[j] = *(const short8*)&Bs[nh + j * 16 + l15][quad * 8];
#pragma unroll
        for (int i = 0; i < 4; ++i)
#pragma unroll
            for (int j = 0; j < 4; ++j)
                acc[i][j] = __builtin_amdgcn_mfma_f32_16x16x32_bf16(af[i], bfv[j], acc[i][j], 0, 0, 0);
        __syncthreads();
    }

#pragma unroll
    for (int i = 0; i < 4; ++i)
#pragma unroll
        for (int j = 0; j < 4; ++j) {
            const int col = n0 + nh + j * 16 + l15;
            const float bb = bias[col];
#pragma unroll
            for (int r = 0; r < 4; ++r) {
                const int row = m0 + mh + i * 16 + quad * 4 + r;
                C[(long)row * N + col] = acc[i][j][r] + bb;
            }
        }
}

// ---------------------------------------------------------------------------
extern "C" void kernel_launch(void* const* d_in, const int* in_sizes, int n_in,
                              void* d_out, int out_size, void* d_ws, size_t ws_size,
                              hipStream_t stream)
{
    const float* x    = (const float*)d_in[0];  // [2,8192,256]
    const float* pos  = (const float*)d_in[1];  // [2,8192,3]
    const float* Wq   = (const float*)d_in[2];  // [256,512]
    const float* Wkv  = (const float*)d_in[3];  // [256,1024]
    const float* Wout = (const float*)d_in[4];  // [512,256]
    const float* bout = (const float*)d_in[5];  // [256]
    float* out = (float*)d_out;                 // [2,8192,256] f32

    const int M = 16384;

    // workspace layout:
    char* ws = (char*)d_ws;
    int*   idxp  = (int*)ws;                          ws += 1 << 19;             // 512 KB
    short* qall  = (short*)ws;                        ws += (long)M * 512 * 2;   // 16 MB
    short* kvall = (short*)ws;                        ws += (long)M * 1024 * 2;  // 32 MB
    short* xb    = (short*)ws;                        ws += (long)M * 256 * 2;   // 8 MB
    short* wqkvt = (short*)ws;                        ws += 1536 * 256 * 2;      // 768 KB
    short* woutt = (short*)ws;                        ws += 256 * 512 * 2;       // 256 KB
    u64*  partial = (u64*)ws;                         ws += (long)128 * 16384 * 8; // 16 MB
    float4* packed = (float4*)ws;                     ws += (long)M * 16;        // 256 KB

    pack_pos<<<64, 256, 0, stream>>>(pos, packed);
    fused_knn_conv<<<5120, 256, 0, stream>>>(packed, partial, x, Wq, Wkv, Wout,
                                             xb, wqkvt, woutt);
    fused_gemm_merge<<<1600, 256, 0, stream>>>(xb, wqkvt, qall, kvall, partial, idxp);
    attn_kernel<<<M / 4, 256, 0, stream>>>(qall, kvall, idxp, qall);   // in-place
    gemm_out<<<dim3(2, 128), 256, 0, stream>>>(qall, woutt, bout, out, 256, 512);
}